// Round 1
// baseline (1236.804 us; speedup 1.0000x reference)
//
#include <hip/hip_runtime.h>

#define DIM 64

// ---- degree: atomic count of dst occurrences ----
__global__ void deg_kernel(const int* __restrict__ dst, float* __restrict__ deg, int E) {
    int i = blockIdx.x * blockDim.x + threadIdx.x;
    if (i < E) atomicAdd(&deg[dst[i]], 1.0f);
}

// ---- dinv = deg>0 ? rsqrt(deg) : 0  (in place, all 3 graphs contiguous) ----
__global__ void dinv_kernel(float* __restrict__ deg, int n) {
    int i = blockIdx.x * blockDim.x + threadIdx.x;
    if (i < n) {
        float d = deg[i];
        deg[i] = (d > 0.0f) ? rsqrtf(d) : 0.0f;
    }
}

// ---- one LGConv layer: xout[dst] += xin[src] * dinv[src]*dinv[dst] * scale ----
// one 64-lane wave per edge, lane = embedding dim (coalesced row gather/scatter)
__global__ void conv_kernel(const int* __restrict__ src, const int* __restrict__ dst,
                            const float* __restrict__ dinv,
                            const float* __restrict__ xin, float* __restrict__ xout,
                            float scale, int E) {
    int gid = blockIdx.x * blockDim.x + threadIdx.x;
    int e = gid >> 6;
    int lane = gid & 63;
    if (e >= E) return;
    int s = src[e];
    int t = dst[e];
    float norm = dinv[s] * dinv[t] * scale;   // wave-uniform
    if (norm != 0.0f) {
        float v = xin[(size_t)s * DIM + lane] * norm;
        atomicAdd(&xout[(size_t)t * DIM + lane], v);
    }
}

// ---- out = (emb + x1) * (1/3)  elementwise over N*64 ----
__global__ void init_out_kernel(const float* __restrict__ emb, const float* __restrict__ x1,
                                float* __restrict__ out, int n) {
    int i = blockIdx.x * blockDim.x + threadIdx.x;
    if (i < n) out[i] = (emb[i] + x1[i]) * (1.0f / 3.0f);
}

// ---- final: feature linears + 6 gathers + dot over D, one wave per edge ----
__global__ void final_kernel(const int* __restrict__ up_e, const int* __restrict__ ut_e,
                             const int* __restrict__ utag_e,
                             const float* __restrict__ src_feat, const float* __restrict__ dst_feat,
                             const float* __restrict__ P, const float* __restrict__ T,
                             const float* __restrict__ G,
                             const float* __restrict__ W_src, const float* __restrict__ b_src,
                             const float* __restrict__ W_dst, const float* __restrict__ b_dst,
                             float* __restrict__ out, int E) {
    int gid = blockIdx.x * blockDim.x + threadIdx.x;
    int e = gid >> 6;
    int d = gid & 63;
    if (e >= E) return;

    // feature-engineering linears: fs[d] = sum_k feat[e,k] * W[k,d] + b[d]
    float fs = b_src[d];
    float fd = b_dst[d];
#pragma unroll
    for (int k = 0; k < 16; ++k) {
        fs += src_feat[(size_t)e * 16 + k] * W_src[k * DIM + d];   // feat: wave-broadcast, W: coalesced
        fd += dst_feat[(size_t)e * 16 + k] * W_dst[k * DIM + d];
    }

    int sp = up_e[e],   dp = up_e[E + e];
    int st = ut_e[e],   dt = ut_e[E + e];
    int sg = utag_e[e], dg = utag_e[E + e];

    float a = (P[(size_t)sp * DIM + d] + T[(size_t)st * DIM + d] + G[(size_t)sg * DIM + d]) * (1.0f / 3.0f) + fs;
    float b = (P[(size_t)dp * DIM + d] + T[(size_t)dt * DIM + d] + G[(size_t)dg * DIM + d]) * (1.0f / 3.0f) + fd;

    float prod = a * b;
#pragma unroll
    for (int off = 32; off > 0; off >>= 1)
        prod += __shfl_down(prod, off, 64);
    if (d == 0) out[e] = prod;
}

extern "C" void kernel_launch(void* const* d_in, const int* in_sizes, int n_in,
                              void* d_out, int out_size, void* d_ws, size_t ws_size,
                              hipStream_t stream) {
    const int*   up_e     = (const int*)d_in[0];
    const int*   ut_e     = (const int*)d_in[1];
    const int*   utag_e   = (const int*)d_in[2];
    const float* src_feat = (const float*)d_in[3];
    const float* dst_feat = (const float*)d_in[4];
    const float* up_emb   = (const float*)d_in[5];
    const float* ut_emb   = (const float*)d_in[6];
    const float* utag_emb = (const float*)d_in[7];
    const float* W_src    = (const float*)d_in[8];
    const float* b_src    = (const float*)d_in[9];
    const float* W_dst    = (const float*)d_in[10];
    const float* b_dst    = (const float*)d_in[11];
    float* out = (float*)d_out;

    const int E  = in_sizes[0] / 2;
    const int NP = in_sizes[5] / DIM;
    const int NT = in_sizes[6] / DIM;
    const int NG = in_sizes[7] / DIM;

    // workspace layout (floats)
    float* ws     = (float*)d_ws;
    float* dinv_p = ws;                       // NP
    float* dinv_t = dinv_p + NP;              // NT
    float* dinv_g = dinv_t + NT;              // NG
    float* x1_p   = dinv_g + NG;              // NP*64
    float* x1_t   = x1_p + (size_t)NP * DIM;  // NT*64
    float* x1_g   = x1_t + (size_t)NT * DIM;  // NG*64
    float* out_p  = x1_g + (size_t)NG * DIM;  // NP*64
    float* out_t  = out_p + (size_t)NP * DIM; // NT*64
    float* out_g  = out_t + (size_t)NT * DIM; // NG*64

    const int NTOT = NP + NT + NG;
    // zero dinv + x1 regions (ws is poisoned to 0xAA before every call)
    hipMemsetAsync(ws, 0, (size_t)NTOT * (1 + DIM) * sizeof(float), stream);

    const int BT = 256;
    dim3 blk(BT);

    // degrees (by dst = edge[1])
    deg_kernel<<<dim3((E + BT - 1) / BT), blk, 0, stream>>>(up_e + E, dinv_p, E);
    deg_kernel<<<dim3((E + BT - 1) / BT), blk, 0, stream>>>(ut_e + E, dinv_t, E);
    deg_kernel<<<dim3((E + BT - 1) / BT), blk, 0, stream>>>(utag_e + E, dinv_g, E);

    // dinv (all three contiguous)
    dinv_kernel<<<dim3((NTOT + BT - 1) / BT), blk, 0, stream>>>(ws, NTOT);

    const int convBlocks = (E * DIM + BT - 1) / BT;

    // graph p
    conv_kernel<<<dim3(convBlocks), blk, 0, stream>>>(up_e, up_e + E, dinv_p, up_emb, x1_p, 1.0f, E);
    init_out_kernel<<<dim3(((NP * DIM) + BT - 1) / BT), blk, 0, stream>>>(up_emb, x1_p, out_p, NP * DIM);
    conv_kernel<<<dim3(convBlocks), blk, 0, stream>>>(up_e, up_e + E, dinv_p, x1_p, out_p, 1.0f / 3.0f, E);

    // graph t
    conv_kernel<<<dim3(convBlocks), blk, 0, stream>>>(ut_e, ut_e + E, dinv_t, ut_emb, x1_t, 1.0f, E);
    init_out_kernel<<<dim3(((NT * DIM) + BT - 1) / BT), blk, 0, stream>>>(ut_emb, x1_t, out_t, NT * DIM);
    conv_kernel<<<dim3(convBlocks), blk, 0, stream>>>(ut_e, ut_e + E, dinv_t, x1_t, out_t, 1.0f / 3.0f, E);

    // graph g
    conv_kernel<<<dim3(convBlocks), blk, 0, stream>>>(utag_e, utag_e + E, dinv_g, utag_emb, x1_g, 1.0f, E);
    init_out_kernel<<<dim3(((NG * DIM) + BT - 1) / BT), blk, 0, stream>>>(utag_emb, x1_g, out_g, NG * DIM);
    conv_kernel<<<dim3(convBlocks), blk, 0, stream>>>(utag_e, utag_e + E, dinv_g, x1_g, out_g, 1.0f / 3.0f, E);

    // final fused: feature linears + aggregation + dot
    final_kernel<<<dim3(convBlocks), blk, 0, stream>>>(up_e, ut_e, utag_e, src_feat, dst_feat,
                                                       out_p, out_t, out_g,
                                                       W_src, b_src, W_dst, b_dst, out, E);
}

// Round 2
// 788.673 us; speedup vs baseline: 1.5682x; 1.5682x over previous
//
#include <hip/hip_runtime.h>

#define DIM 64

struct __align__(8) Edge { int s; float w; };

// ---- degree count for all 3 graphs in one launch (int atomics) ----
__global__ void deg3_kernel(const int* __restrict__ d0, const int* __restrict__ d1,
                            const int* __restrict__ d2, int* __restrict__ degi,
                            int NP, int NT, int E) {
    int i = blockIdx.x * blockDim.x + threadIdx.x;
    if (i >= 3 * E) return;
    int g = i / E;
    int j = i - g * E;
    const int* dd = (g == 0) ? d0 : (g == 1) ? d1 : d2;
    int base = (g == 0) ? 0 : (g == 1) ? NP : NP + NT;
    atomicAdd(&degi[base + dd[j]], 1);
}

// ---- dinv = deg>0 ? rsqrt(deg) : 0 ----
__global__ void dinv_kernel(const int* __restrict__ degi, float* __restrict__ dinv, int n) {
    int i = blockIdx.x * blockDim.x + threadIdx.x;
    if (i < n) {
        int d = degi[i];
        dinv[i] = (d > 0) ? rsqrtf((float)d) : 0.0f;
    }
}

// ---- exclusive scan of degrees -> offsets + cursor copy; one block per graph ----
__global__ void scan_kernel(const int* __restrict__ degi, int* __restrict__ offs,
                            int* __restrict__ cur, int NP, int NT, int NG) {
    int g = blockIdx.x;
    int base = (g == 0) ? 0 : (g == 1) ? NP : NP + NT;
    int n    = (g == 0) ? NP : (g == 1) ? NT : NG;
    const int* d = degi + base;
    int* o = offs + base + g;   // each graph's offsets array is n+1 long
    int* c = cur + base;
    __shared__ int wsum[16];
    __shared__ int stotal;
    int lane = threadIdx.x & 63;
    int wid  = threadIdx.x >> 6;
    int running = 0;
    for (int chunk = 0; chunk < n; chunk += 1024) {
        int i = chunk + threadIdx.x;
        int v = (i < n) ? d[i] : 0;
        int x = v;
#pragma unroll
        for (int s = 1; s < 64; s <<= 1) {
            int y = __shfl_up(x, s, 64);
            if (lane >= s) x += y;
        }
        if (lane == 63) wsum[wid] = x;
        __syncthreads();
        if (threadIdx.x < 16) {
            int ws = wsum[threadIdx.x];
#pragma unroll
            for (int s = 1; s < 16; s <<= 1) {
                int y = __shfl_up(ws, s, 16);
                if ((threadIdx.x & 15) >= s) ws += y;
            }
            wsum[threadIdx.x] = ws;
            if (threadIdx.x == 15) stotal = ws;
        }
        __syncthreads();
        int pre = (wid > 0) ? wsum[wid - 1] : 0;
        int excl = running + pre + (x - v);
        if (i < n) { o[i] = excl; c[i] = excl; }
        running += stotal;
        __syncthreads();   // protect wsum/stotal before next chunk overwrites
    }
    if (threadIdx.x == 0) o[n] = running;
}

// ---- permute edges into dst-sorted CSR order, precompute norm ----
__global__ void permute_kernel(const int* __restrict__ src, const int* __restrict__ dst,
                               const float* __restrict__ dinv, int* __restrict__ cur,
                               Edge* __restrict__ ep, int E) {
    int i = blockIdx.x * blockDim.x + threadIdx.x;
    if (i >= E) return;
    int s = src[i], t = dst[i];
    int p = atomicAdd(&cur[t], 1);
    Edge e;
    e.s = s;
    e.w = dinv[s] * dinv[t];
    ep[p] = e;
}

// ---- pull-based conv layer 1: x1[n] = sum_in x[src]*norm  (no atomics) ----
__global__ void conv_csr1(const int* __restrict__ offs, const Edge* __restrict__ ep,
                          const float* __restrict__ xin, float* __restrict__ xout, int N) {
    int gid = blockIdx.x * blockDim.x + threadIdx.x;
    int n = gid >> 6, d = gid & 63;
    if (n >= N) return;
    int beg = offs[n], end = offs[n + 1];
    float acc = 0.0f;
    int k = beg;
    for (; k + 1 < end; k += 2) {
        Edge e0 = ep[k], e1 = ep[k + 1];
        float v0 = xin[(size_t)e0.s * DIM + d];
        float v1 = xin[(size_t)e1.s * DIM + d];
        acc = fmaf(v0, e0.w, acc);
        acc = fmaf(v1, e1.w, acc);
    }
    if (k < end) {
        Edge e0 = ep[k];
        acc = fmaf(xin[(size_t)e0.s * DIM + d], e0.w, acc);
    }
    xout[(size_t)n * DIM + d] = acc;
}

// ---- pull-based conv layer 2 fused with final accumulation:
//      out[n] = (emb[n] + x1[n] + conv(x1)[n]) / 3 ----
__global__ void conv_csr2(const int* __restrict__ offs, const Edge* __restrict__ ep,
                          const float* __restrict__ emb, const float* __restrict__ x1,
                          float* __restrict__ out, int N) {
    int gid = blockIdx.x * blockDim.x + threadIdx.x;
    int n = gid >> 6, d = gid & 63;
    if (n >= N) return;
    int beg = offs[n], end = offs[n + 1];
    float acc = 0.0f;
    int k = beg;
    for (; k + 1 < end; k += 2) {
        Edge e0 = ep[k], e1 = ep[k + 1];
        float v0 = x1[(size_t)e0.s * DIM + d];
        float v1 = x1[(size_t)e1.s * DIM + d];
        acc = fmaf(v0, e0.w, acc);
        acc = fmaf(v1, e1.w, acc);
    }
    if (k < end) {
        Edge e0 = ep[k];
        acc = fmaf(x1[(size_t)e0.s * DIM + d], e0.w, acc);
    }
    size_t idx = (size_t)n * DIM + d;
    out[idx] = (emb[idx] + x1[idx] + acc) * (1.0f / 3.0f);
}

// ---- final: feature linears + 6 gathers + dot; 16 lanes x float4 per edge ----
__global__ void final_kernel(const int* __restrict__ up_e, const int* __restrict__ ut_e,
                             const int* __restrict__ utag_e,
                             const float* __restrict__ src_feat, const float* __restrict__ dst_feat,
                             const float* __restrict__ O,   // outf base; T rows at +NP, G at +NP+NT
                             const float* __restrict__ W_src, const float* __restrict__ b_src,
                             const float* __restrict__ W_dst, const float* __restrict__ b_dst,
                             float* __restrict__ out, int E, int NP, int NT) {
    int gid = blockIdx.x * blockDim.x + threadIdx.x;
    int e = gid >> 4;
    int l = gid & 15;            // handles dims 4l..4l+3
    if (e >= E) return;
    int lane = threadIdx.x & 63;
    int gbase = lane & 48;       // first lane of this 16-lane group

    // edge endpoint indices (broadcast loads within group)
    int sp = up_e[e],   dp = up_e[E + e];
    int st = ut_e[e],   dt = ut_e[E + e];
    int sg = utag_e[e], dg = utag_e[E + e];

    // each lane loads one feature scalar, broadcast via shfl
    float myfs = src_feat[(size_t)e * 16 + l];
    float myfd = dst_feat[(size_t)e * 16 + l];

    const float4* W_s4 = (const float4*)W_src;
    const float4* W_d4 = (const float4*)W_dst;
    float4 fs = ((const float4*)b_src)[l];
    float4 fd = ((const float4*)b_dst)[l];
#pragma unroll
    for (int k = 0; k < 16; ++k) {
        float sf = __shfl(myfs, gbase + k, 64);
        float df = __shfl(myfd, gbase + k, 64);
        float4 ws = W_s4[k * 16 + l];
        float4 wd = W_d4[k * 16 + l];
        fs.x = fmaf(ws.x, sf, fs.x); fs.y = fmaf(ws.y, sf, fs.y);
        fs.z = fmaf(ws.z, sf, fs.z); fs.w = fmaf(ws.w, sf, fs.w);
        fd.x = fmaf(wd.x, df, fd.x); fd.y = fmaf(wd.y, df, fd.y);
        fd.z = fmaf(wd.z, df, fd.z); fd.w = fmaf(wd.w, df, fd.w);
    }

    const float4* O4 = (const float4*)O;   // row stride = 16 float4
    float4 ap = O4[(size_t)sp * 16 + l];
    float4 at = O4[((size_t)NP + st) * 16 + l];
    float4 ag = O4[((size_t)NP + NT + sg) * 16 + l];
    float4 bp = O4[(size_t)dp * 16 + l];
    float4 bt = O4[((size_t)NP + dt) * 16 + l];
    float4 bg = O4[((size_t)NP + NT + dg) * 16 + l];

    const float third = 1.0f / 3.0f;
    float4 a, b;
    a.x = (ap.x + at.x + ag.x) * third + fs.x;
    a.y = (ap.y + at.y + ag.y) * third + fs.y;
    a.z = (ap.z + at.z + ag.z) * third + fs.z;
    a.w = (ap.w + at.w + ag.w) * third + fs.w;
    b.x = (bp.x + bt.x + bg.x) * third + fd.x;
    b.y = (bp.y + bt.y + bg.y) * third + fd.y;
    b.z = (bp.z + bt.z + bg.z) * third + fd.z;
    b.w = (bp.w + bt.w + bg.w) * third + fd.w;

    float prod = a.x * b.x + a.y * b.y + a.z * b.z + a.w * b.w;
    prod += __shfl_xor(prod, 8, 64);
    prod += __shfl_xor(prod, 4, 64);
    prod += __shfl_xor(prod, 2, 64);
    prod += __shfl_xor(prod, 1, 64);
    if (l == 0) out[e] = prod;
}

extern "C" void kernel_launch(void* const* d_in, const int* in_sizes, int n_in,
                              void* d_out, int out_size, void* d_ws, size_t ws_size,
                              hipStream_t stream) {
    const int*   up_e     = (const int*)d_in[0];
    const int*   ut_e     = (const int*)d_in[1];
    const int*   utag_e   = (const int*)d_in[2];
    const float* src_feat = (const float*)d_in[3];
    const float* dst_feat = (const float*)d_in[4];
    const float* up_emb   = (const float*)d_in[5];
    const float* ut_emb   = (const float*)d_in[6];
    const float* utag_emb = (const float*)d_in[7];
    const float* W_src    = (const float*)d_in[8];
    const float* b_src    = (const float*)d_in[9];
    const float* W_dst    = (const float*)d_in[10];
    const float* b_dst    = (const float*)d_in[11];
    float* out = (float*)d_out;

    const int E  = in_sizes[0] / 2;
    const int NP = in_sizes[5] / DIM;
    const int NT = in_sizes[6] / DIM;
    const int NG = in_sizes[7] / DIM;
    const int NTOT = NP + NT + NG;

    // ---- workspace layout (reuse ep and x1 across graphs) ----
    char* w = (char*)d_ws;
    int*  degi = (int*)w;                       w += (size_t)NTOT * 4;
    int*  offs = (int*)w;                       w += (size_t)(NTOT + 3) * 4;
    int*  cur  = (int*)w;                       w += (size_t)NTOT * 4;
    w = (char*)(((uintptr_t)w + 15) & ~(uintptr_t)15);
    Edge* ep   = (Edge*)w;                      w += (size_t)E * sizeof(Edge);
    float* dinv = (float*)w;                    w += (size_t)NTOT * 4;
    w = (char*)(((uintptr_t)w + 15) & ~(uintptr_t)15);
    float* x1   = (float*)w;                    w += (size_t)NP * DIM * 4;  // NP is the max N
    float* outf = (float*)w;                    // NTOT*64 floats

    const int BT = 256;

    // degree counts (dst = edge[1] = second half of each edge array)
    hipMemsetAsync(degi, 0, (size_t)NTOT * 4, stream);
    deg3_kernel<<<dim3((3 * E + BT - 1) / BT), dim3(BT), 0, stream>>>(
        up_e + E, ut_e + E, utag_e + E, degi, NP, NT, E);
    dinv_kernel<<<dim3((NTOT + BT - 1) / BT), dim3(BT), 0, stream>>>(degi, dinv, NTOT);
    scan_kernel<<<dim3(3), dim3(1024), 0, stream>>>(degi, offs, cur, NP, NT, NG);

    const int permBlocks = (E + BT - 1) / BT;

    // per-graph: build CSR, conv layer1, conv layer2 (fused epilogue)
    {   // graph p
        permute_kernel<<<dim3(permBlocks), dim3(BT), 0, stream>>>(
            up_e, up_e + E, dinv, cur, ep, E);
        int nb = (NP * DIM + BT - 1) / BT;
        conv_csr1<<<dim3(nb), dim3(BT), 0, stream>>>(offs, ep, up_emb, x1, NP);
        conv_csr2<<<dim3(nb), dim3(BT), 0, stream>>>(offs, ep, up_emb, x1, outf, NP);
    }
    {   // graph t
        permute_kernel<<<dim3(permBlocks), dim3(BT), 0, stream>>>(
            ut_e, ut_e + E, dinv + NP, cur + NP, ep, E);
        int nb = (NT * DIM + BT - 1) / BT;
        conv_csr1<<<dim3(nb), dim3(BT), 0, stream>>>(offs + NP + 1, ep, ut_emb, x1, NT);
        conv_csr2<<<dim3(nb), dim3(BT), 0, stream>>>(offs + NP + 1, ep, ut_emb, x1,
                                                     outf + (size_t)NP * DIM, NT);
    }
    {   // graph g
        permute_kernel<<<dim3(permBlocks), dim3(BT), 0, stream>>>(
            utag_e, utag_e + E, dinv + NP + NT, cur + NP + NT, ep, E);
        int nb = (NG * DIM + BT - 1) / BT;
        conv_csr1<<<dim3(nb), dim3(BT), 0, stream>>>(offs + NP + NT + 2, ep, utag_emb, x1, NG);
        conv_csr2<<<dim3(nb), dim3(BT), 0, stream>>>(offs + NP + NT + 2, ep, utag_emb, x1,
                                                     outf + (size_t)(NP + NT) * DIM, NG);
    }

    // final fused: feature linears + aggregation + dot (16 lanes x float4 per edge)
    final_kernel<<<dim3(((size_t)E * 16 + BT - 1) / BT), dim3(BT), 0, stream>>>(
        up_e, ut_e, utag_e, src_feat, dst_feat, outf,
        W_src, b_src, W_dst, b_dst, out, E, NP, NT);
}

// Round 3
// 576.257 us; speedup vs baseline: 2.1463x; 1.3686x over previous
//
#include <hip/hip_runtime.h>

#define DIM 64

struct __align__(8) Edge { int s; float w; };

__device__ __forceinline__ float4 fma4(float4 a, float s, float4 c) {
    c.x = fmaf(a.x, s, c.x); c.y = fmaf(a.y, s, c.y);
    c.z = fmaf(a.z, s, c.z); c.w = fmaf(a.w, s, c.w);
    return c;
}

// ---- degree count for all 3 graphs in one launch (int atomics) ----
__global__ void deg3_kernel(const int* __restrict__ d0, const int* __restrict__ d1,
                            const int* __restrict__ d2, int* __restrict__ degi,
                            int NP, int NT, int E) {
    int i = blockIdx.x * blockDim.x + threadIdx.x;
    if (i >= 3 * E) return;
    int g = i / E;
    int j = i - g * E;
    const int* dd = (g == 0) ? d0 : (g == 1) ? d1 : d2;
    int base = (g == 0) ? 0 : (g == 1) ? NP : NP + NT;
    atomicAdd(&degi[base + dd[j]], 1);
}

// ---- dinv = deg>0 ? rsqrt(deg) : 0 ----
__global__ void dinv_kernel(const int* __restrict__ degi, float* __restrict__ dinv, int n) {
    int i = blockIdx.x * blockDim.x + threadIdx.x;
    if (i < n) {
        int d = degi[i];
        dinv[i] = (d > 0) ? rsqrtf((float)d) : 0.0f;
    }
}

// ---- parallel scan, stage 1: per-block (256-elem) sums ----
__global__ void block_sums(const int* __restrict__ degi, int* __restrict__ bsum, int n) {
    int i = blockIdx.x * 256 + threadIdx.x;
    int v = (i < n) ? degi[i] : 0;
#pragma unroll
    for (int s = 1; s < 64; s <<= 1) v += __shfl_xor(v, s, 64);
    __shared__ int ws[4];
    if ((threadIdx.x & 63) == 0) ws[threadIdx.x >> 6] = v;
    __syncthreads();
    if (threadIdx.x == 0) bsum[blockIdx.x] = ws[0] + ws[1] + ws[2] + ws[3];
}

// ---- stage 2: exclusive scan of block sums (single block, nb <= 1024) ----
__global__ void scan_bsums(int* __restrict__ bsum, int nb) {
    int lane = threadIdx.x & 63, wid = threadIdx.x >> 6;
    int v = (threadIdx.x < nb) ? bsum[threadIdx.x] : 0;
    int x = v;
#pragma unroll
    for (int s = 1; s < 64; s <<= 1) {
        int y = __shfl_up(x, s, 64);
        if (lane >= s) x += y;
    }
    __shared__ int ws[16];
    if (lane == 63) ws[wid] = x;
    __syncthreads();
    int pre = 0;
    for (int w2 = 0; w2 < wid; ++w2) pre += ws[w2];
    if (threadIdx.x < nb) bsum[threadIdx.x] = pre + x - v;   // exclusive
}

// ---- stage 3: global exclusive offsets + cursor copy ----
__global__ void scatter_offs(const int* __restrict__ degi, const int* __restrict__ bpre,
                             int* __restrict__ offs, int* __restrict__ cur,
                             int n, int total) {
    int i = blockIdx.x * 256 + threadIdx.x;
    int lane = threadIdx.x & 63, wid = threadIdx.x >> 6;
    int v = (i < n) ? degi[i] : 0;
    int x = v;
#pragma unroll
    for (int s = 1; s < 64; s <<= 1) {
        int y = __shfl_up(x, s, 64);
        if (lane >= s) x += y;
    }
    __shared__ int ws[4];
    if (lane == 63) ws[wid] = x;
    __syncthreads();
    int pre = bpre[blockIdx.x];
    for (int w2 = 0; w2 < wid; ++w2) pre += ws[w2];
    if (i < n) { int e = pre + x - v; offs[i] = e; cur[i] = e; }
    if (i == 0) offs[n] = total;
}

// ---- permute edges into dst-sorted CSR order (per graph; global cursors) ----
__global__ void permute_kernel(const int* __restrict__ src, const int* __restrict__ dst,
                               const float* __restrict__ dinv, int* __restrict__ cur,
                               Edge* __restrict__ ep, int ebase, int E) {
    int i = blockIdx.x * blockDim.x + threadIdx.x;
    if (i >= E) return;
    int s = src[i], t = dst[i];
    int p = atomicAdd(&cur[t], 1) - ebase;
    Edge e;
    e.s = s;
    e.w = dinv[s] * dinv[t];
    ep[p] = e;
}

// ---- conv layer 1: x1[n] = sum_in x[src]*w ; 16 lanes x float4, 4 nodes/wave ----
__global__ void conv_csr1(const int* __restrict__ offs, int ebase,
                          const Edge* __restrict__ ep,
                          const float4* __restrict__ xin, float4* __restrict__ xout, int N) {
    int gid = blockIdx.x * blockDim.x + threadIdx.x;
    int n = gid >> 4, l = gid & 15;
    if (n >= N) return;
    int beg = offs[n] - ebase, end = offs[n + 1] - ebase;
    float4 acc = {0.f, 0.f, 0.f, 0.f};
    int k = beg;
    for (; k + 1 < end; k += 2) {
        Edge e0 = ep[k], e1 = ep[k + 1];
        float4 v0 = xin[(size_t)e0.s * 16 + l];
        float4 v1 = xin[(size_t)e1.s * 16 + l];
        acc = fma4(v0, e0.w, acc);
        acc = fma4(v1, e1.w, acc);
    }
    if (k < end) {
        Edge e0 = ep[k];
        acc = fma4(xin[(size_t)e0.s * 16 + l], e0.w, acc);
    }
    xout[(size_t)n * 16 + l] = acc;
}

// ---- conv layer 2 fused epilogue: out[n] = (emb + x1 + conv(x1)) / 3 ----
__global__ void conv_csr2(const int* __restrict__ offs, int ebase,
                          const Edge* __restrict__ ep,
                          const float4* __restrict__ emb, const float4* __restrict__ x1,
                          float4* __restrict__ out, int N) {
    int gid = blockIdx.x * blockDim.x + threadIdx.x;
    int n = gid >> 4, l = gid & 15;
    if (n >= N) return;
    int beg = offs[n] - ebase, end = offs[n + 1] - ebase;
    float4 acc = {0.f, 0.f, 0.f, 0.f};
    int k = beg;
    for (; k + 1 < end; k += 2) {
        Edge e0 = ep[k], e1 = ep[k + 1];
        float4 v0 = x1[(size_t)e0.s * 16 + l];
        float4 v1 = x1[(size_t)e1.s * 16 + l];
        acc = fma4(v0, e0.w, acc);
        acc = fma4(v1, e1.w, acc);
    }
    if (k < end) {
        Edge e0 = ep[k];
        acc = fma4(x1[(size_t)e0.s * 16 + l], e0.w, acc);
    }
    size_t idx = (size_t)n * 16 + l;
    float4 em = emb[idx], x = x1[idx];
    const float third = 1.0f / 3.0f;
    float4 o;
    o.x = (em.x + x.x + acc.x) * third;
    o.y = (em.y + x.y + acc.y) * third;
    o.z = (em.z + x.z + acc.z) * third;
    o.w = (em.w + x.w + acc.w) * third;
    out[idx] = o;
}

// ---- final: 2 edges per 16-lane group for 2x memory-level parallelism ----
__global__ void final_kernel(const int* __restrict__ up_e, const int* __restrict__ ut_e,
                             const int* __restrict__ utag_e,
                             const float* __restrict__ src_feat, const float* __restrict__ dst_feat,
                             const float4* __restrict__ O4,
                             const float4* __restrict__ W_s4, const float4* __restrict__ b_s4,
                             const float4* __restrict__ W_d4, const float4* __restrict__ b_d4,
                             float* __restrict__ out, int E, int NP, int NT) {
    int gid = blockIdx.x * blockDim.x + threadIdx.x;
    int grp = gid >> 4;
    int l = gid & 15;
    int e0 = grp * 2;
    if (e0 >= E) return;
    int e1 = e0 + 1;
    bool has1 = (e1 < E);
    int e1c = has1 ? e1 : e0;
    int lane = threadIdx.x & 63;
    int gbase = lane & 48;

    // endpoint indices
    int sp0 = up_e[e0],   dp0 = up_e[E + e0];
    int st0 = ut_e[e0],   dt0 = ut_e[E + e0];
    int sg0 = utag_e[e0], dg0 = utag_e[E + e0];
    int sp1 = up_e[e1c],   dp1 = up_e[E + e1c];
    int st1 = ut_e[e1c],   dt1 = ut_e[E + e1c];
    int sg1 = utag_e[e1c], dg1 = utag_e[E + e1c];

    // one feature scalar per lane, broadcast via shfl in the FMA loop
    float f_s0 = src_feat[(size_t)e0 * 16 + l];
    float f_d0 = dst_feat[(size_t)e0 * 16 + l];
    float f_s1 = src_feat[(size_t)e1c * 16 + l];
    float f_d1 = dst_feat[(size_t)e1c * 16 + l];

    // issue all 12 row gathers up front (independent streams)
    float4 ap0 = O4[(size_t)sp0 * 16 + l];
    float4 at0 = O4[((size_t)NP + st0) * 16 + l];
    float4 ag0 = O4[((size_t)NP + NT + sg0) * 16 + l];
    float4 bp0 = O4[(size_t)dp0 * 16 + l];
    float4 bt0 = O4[((size_t)NP + dt0) * 16 + l];
    float4 bg0 = O4[((size_t)NP + NT + dg0) * 16 + l];
    float4 ap1 = O4[(size_t)sp1 * 16 + l];
    float4 at1 = O4[((size_t)NP + st1) * 16 + l];
    float4 ag1 = O4[((size_t)NP + NT + sg1) * 16 + l];
    float4 bp1 = O4[(size_t)dp1 * 16 + l];
    float4 bt1 = O4[((size_t)NP + dt1) * 16 + l];
    float4 bg1 = O4[((size_t)NP + NT + dg1) * 16 + l];

    float4 fs0 = b_s4[l], fd0 = b_d4[l];
    float4 fs1 = fs0,     fd1 = fd0;
#pragma unroll
    for (int k = 0; k < 16; ++k) {
        float4 ws = W_s4[k * 16 + l];
        float4 wd = W_d4[k * 16 + l];
        float a0 = __shfl(f_s0, gbase + k, 64);
        float c0 = __shfl(f_d0, gbase + k, 64);
        float a1 = __shfl(f_s1, gbase + k, 64);
        float c1 = __shfl(f_d1, gbase + k, 64);
        fs0 = fma4(ws, a0, fs0); fd0 = fma4(wd, c0, fd0);
        fs1 = fma4(ws, a1, fs1); fd1 = fma4(wd, c1, fd1);
    }

    const float third = 1.0f / 3.0f;
    float4 a, b;
    a.x = (ap0.x + at0.x + ag0.x) * third + fs0.x;
    a.y = (ap0.y + at0.y + ag0.y) * third + fs0.y;
    a.z = (ap0.z + at0.z + ag0.z) * third + fs0.z;
    a.w = (ap0.w + at0.w + ag0.w) * third + fs0.w;
    b.x = (bp0.x + bt0.x + bg0.x) * third + fd0.x;
    b.y = (bp0.y + bt0.y + bg0.y) * third + fd0.y;
    b.z = (bp0.z + bt0.z + bg0.z) * third + fd0.z;
    b.w = (bp0.w + bt0.w + bg0.w) * third + fd0.w;
    float prod0 = a.x * b.x + a.y * b.y + a.z * b.z + a.w * b.w;

    a.x = (ap1.x + at1.x + ag1.x) * third + fs1.x;
    a.y = (ap1.y + at1.y + ag1.y) * third + fs1.y;
    a.z = (ap1.z + at1.z + ag1.z) * third + fs1.z;
    a.w = (ap1.w + at1.w + ag1.w) * third + fs1.w;
    b.x = (bp1.x + bt1.x + bg1.x) * third + fd1.x;
    b.y = (bp1.y + bt1.y + bg1.y) * third + fd1.y;
    b.z = (bp1.z + bt1.z + bg1.z) * third + fd1.z;
    b.w = (bp1.w + bt1.w + bg1.w) * third + fd1.w;
    float prod1 = a.x * b.x + a.y * b.y + a.z * b.z + a.w * b.w;

    prod0 += __shfl_xor(prod0, 8, 64);
    prod0 += __shfl_xor(prod0, 4, 64);
    prod0 += __shfl_xor(prod0, 2, 64);
    prod0 += __shfl_xor(prod0, 1, 64);
    prod1 += __shfl_xor(prod1, 8, 64);
    prod1 += __shfl_xor(prod1, 4, 64);
    prod1 += __shfl_xor(prod1, 2, 64);
    prod1 += __shfl_xor(prod1, 1, 64);
    if (l == 0) {
        out[e0] = prod0;
        if (has1) out[e1] = prod1;
    }
}

extern "C" void kernel_launch(void* const* d_in, const int* in_sizes, int n_in,
                              void* d_out, int out_size, void* d_ws, size_t ws_size,
                              hipStream_t stream) {
    const int*   up_e     = (const int*)d_in[0];
    const int*   ut_e     = (const int*)d_in[1];
    const int*   utag_e   = (const int*)d_in[2];
    const float* src_feat = (const float*)d_in[3];
    const float* dst_feat = (const float*)d_in[4];
    const float* up_emb   = (const float*)d_in[5];
    const float* ut_emb   = (const float*)d_in[6];
    const float* utag_emb = (const float*)d_in[7];
    const float* W_src    = (const float*)d_in[8];
    const float* b_src    = (const float*)d_in[9];
    const float* W_dst    = (const float*)d_in[10];
    const float* b_dst    = (const float*)d_in[11];
    float* out = (float*)d_out;

    const int E  = in_sizes[0] / 2;
    const int NP = in_sizes[5] / DIM;
    const int NT = in_sizes[6] / DIM;
    const int NG = in_sizes[7] / DIM;
    const int NTOT = NP + NT + NG;
    const int NB = (NTOT + 255) / 256;          // scan blocks

    // ---- workspace layout ----
    char* w = (char*)d_ws;
    int*  degi = (int*)w;                       w += (size_t)NTOT * 4;
    int*  offs = (int*)w;                       w += (size_t)(NTOT + 1) * 4;
    int*  cur  = (int*)w;                       w += (size_t)NTOT * 4;
    int*  bsum = (int*)w;                       w += (size_t)1024 * 4;
    float* dinv = (float*)w;                    w += (size_t)NTOT * 4;
    w = (char*)(((uintptr_t)w + 15) & ~(uintptr_t)15);
    Edge* ep   = (Edge*)w;                      w += (size_t)E * sizeof(Edge);
    w = (char*)(((uintptr_t)w + 15) & ~(uintptr_t)15);
    float* x1   = (float*)w;                    w += (size_t)NP * DIM * 4;  // NP = max graph size
    float* outf = (float*)w;                    // NTOT*64 floats

    const int BT = 256;

    // degree counts (dst = edge[1] = second half of each edge array)
    hipMemsetAsync(degi, 0, (size_t)NTOT * 4, stream);
    deg3_kernel<<<dim3((3 * E + BT - 1) / BT), dim3(BT), 0, stream>>>(
        up_e + E, ut_e + E, utag_e + E, degi, NP, NT, E);
    dinv_kernel<<<dim3((NTOT + BT - 1) / BT), dim3(BT), 0, stream>>>(degi, dinv, NTOT);

    // global parallel exclusive scan (graph bases are statically 0, E, 2E)
    block_sums<<<dim3(NB), dim3(BT), 0, stream>>>(degi, bsum, NTOT);
    scan_bsums<<<dim3(1), dim3(1024), 0, stream>>>(bsum, NB);
    scatter_offs<<<dim3(NB), dim3(BT), 0, stream>>>(degi, bsum, offs, cur, NTOT, 3 * E);

    const int permBlocks = (E + BT - 1) / BT;

    // per-graph: build CSR, conv layer1, conv layer2 (ep buffer reused serially)
    {   // graph p (ebase 0)
        permute_kernel<<<dim3(permBlocks), dim3(BT), 0, stream>>>(
            up_e, up_e + E, dinv, cur, ep, 0, E);
        int nb = ((size_t)NP * 16 + BT - 1) / BT;
        conv_csr1<<<dim3(nb), dim3(BT), 0, stream>>>(offs, 0, ep,
            (const float4*)up_emb, (float4*)x1, NP);
        conv_csr2<<<dim3(nb), dim3(BT), 0, stream>>>(offs, 0, ep,
            (const float4*)up_emb, (const float4*)x1, (float4*)outf, NP);
    }
    {   // graph t (ebase E)
        permute_kernel<<<dim3(permBlocks), dim3(BT), 0, stream>>>(
            ut_e, ut_e + E, dinv + NP, cur + NP, ep, E, E);
        int nb = ((size_t)NT * 16 + BT - 1) / BT;
        conv_csr1<<<dim3(nb), dim3(BT), 0, stream>>>(offs + NP, E, ep,
            (const float4*)ut_emb, (float4*)x1, NT);
        conv_csr2<<<dim3(nb), dim3(BT), 0, stream>>>(offs + NP, E, ep,
            (const float4*)ut_emb, (const float4*)x1,
            (float4*)(outf + (size_t)NP * DIM), NT);
    }
    {   // graph g (ebase 2E)
        permute_kernel<<<dim3(permBlocks), dim3(BT), 0, stream>>>(
            utag_e, utag_e + E, dinv + NP + NT, cur + NP + NT, ep, 2 * E, E);
        int nb = ((size_t)NG * 16 + BT - 1) / BT;
        conv_csr1<<<dim3(nb), dim3(BT), 0, stream>>>(offs + NP + NT, 2 * E, ep,
            (const float4*)utag_emb, (float4*)x1, NG);
        conv_csr2<<<dim3(nb), dim3(BT), 0, stream>>>(offs + NP + NT, 2 * E, ep,
            (const float4*)utag_emb, (const float4*)x1,
            (float4*)(outf + (size_t)(NP + NT) * DIM), NG);
    }

    // final: 2 edges per 16-lane group
    int groups = (E + 1) / 2;
    final_kernel<<<dim3(((size_t)groups * 16 + BT - 1) / BT), dim3(BT), 0, stream>>>(
        up_e, ut_e, utag_e, src_feat, dst_feat, (const float4*)outf,
        (const float4*)W_src, (const float4*)b_src,
        (const float4*)W_dst, (const float4*)b_dst, out, E, NP, NT);
}

// Round 4
// 503.807 us; speedup vs baseline: 2.4549x; 1.1438x over previous
//
#include <hip/hip_runtime.h>

#define DIM 64

struct __align__(8) Edge { int s; float w; };

__device__ __forceinline__ float bf2f(unsigned short u) {
    union { unsigned int i; float f; } v; v.i = ((unsigned int)u) << 16; return v.f;
}
__device__ __forceinline__ unsigned short f2bf(float f) {
    union { float f; unsigned int i; } v; v.f = f;
    unsigned int r = v.i + 0x7fff + ((v.i >> 16) & 1);   // RNE (no NaN inputs here)
    return (unsigned short)(r >> 16);
}
__device__ __forceinline__ float4 u2f4(ushort4 u) {
    float4 f; f.x = bf2f(u.x); f.y = bf2f(u.y); f.z = bf2f(u.z); f.w = bf2f(u.w);
    return f;
}
__device__ __forceinline__ ushort4 f2u4(float4 f) {
    ushort4 u; u.x = f2bf(f.x); u.y = f2bf(f.y); u.z = f2bf(f.z); u.w = f2bf(f.w);
    return u;
}
__device__ __forceinline__ float4 fma4(float4 a, float s, float4 c) {
    c.x = fmaf(a.x, s, c.x); c.y = fmaf(a.y, s, c.y);
    c.z = fmaf(a.z, s, c.z); c.w = fmaf(a.w, s, c.w);
    return c;
}

// ---- degree count for all 3 graphs in one launch (int atomics) ----
__global__ void deg3_kernel(const int* __restrict__ d0, const int* __restrict__ d1,
                            const int* __restrict__ d2, int* __restrict__ degi,
                            int NP, int NT, int E) {
    int i = blockIdx.x * blockDim.x + threadIdx.x;
    if (i >= 3 * E) return;
    int g = i / E;
    int j = i - g * E;
    const int* dd = (g == 0) ? d0 : (g == 1) ? d1 : d2;
    int base = (g == 0) ? 0 : (g == 1) ? NP : NP + NT;
    atomicAdd(&degi[base + dd[j]], 1);
}

// ---- dinv = deg>0 ? rsqrt(deg) : 0 ----
__global__ void dinv_kernel(const int* __restrict__ degi, float* __restrict__ dinv, int n) {
    int i = blockIdx.x * blockDim.x + threadIdx.x;
    if (i < n) {
        int d = degi[i];
        dinv[i] = (d > 0) ? rsqrtf((float)d) : 0.0f;
    }
}

// ---- convert the 3 fp32 emb tables into one unified bf16 table ----
__global__ void cvt3_kernel(const float4* __restrict__ e0, const float4* __restrict__ e1,
                            const float4* __restrict__ e2, ushort4* __restrict__ dst,
                            int NP, int NT, int NG) {
    int i = blockIdx.x * blockDim.x + threadIdx.x;
    int np16 = NP * 16, nt16 = NT * 16, ng16 = NG * 16;
    if (i >= np16 + nt16 + ng16) return;
    const float4* s; int j;
    if (i < np16)              { s = e0; j = i; }
    else if (i < np16 + nt16)  { s = e1; j = i - np16; }
    else                       { s = e2; j = i - np16 - nt16; }
    dst[i] = f2u4(s[j]);
}

// ---- parallel scan, stage 1: per-block (256-elem) sums ----
__global__ void block_sums(const int* __restrict__ degi, int* __restrict__ bsum, int n) {
    int i = blockIdx.x * 256 + threadIdx.x;
    int v = (i < n) ? degi[i] : 0;
#pragma unroll
    for (int s = 1; s < 64; s <<= 1) v += __shfl_xor(v, s, 64);
    __shared__ int ws[4];
    if ((threadIdx.x & 63) == 0) ws[threadIdx.x >> 6] = v;
    __syncthreads();
    if (threadIdx.x == 0) bsum[blockIdx.x] = ws[0] + ws[1] + ws[2] + ws[3];
}

// ---- stage 2: exclusive scan of block sums (single block, nb <= 1024) ----
__global__ void scan_bsums(int* __restrict__ bsum, int nb) {
    int lane = threadIdx.x & 63, wid = threadIdx.x >> 6;
    int v = (threadIdx.x < nb) ? bsum[threadIdx.x] : 0;
    int x = v;
#pragma unroll
    for (int s = 1; s < 64; s <<= 1) {
        int y = __shfl_up(x, s, 64);
        if (lane >= s) x += y;
    }
    __shared__ int ws[16];
    if (lane == 63) ws[wid] = x;
    __syncthreads();
    int pre = 0;
    for (int w2 = 0; w2 < wid; ++w2) pre += ws[w2];
    if (threadIdx.x < nb) bsum[threadIdx.x] = pre + x - v;   // exclusive
}

// ---- stage 3: global exclusive offsets + cursor copy ----
__global__ void scatter_offs(const int* __restrict__ degi, const int* __restrict__ bpre,
                             int* __restrict__ offs, int* __restrict__ cur,
                             int n, int total) {
    int i = blockIdx.x * 256 + threadIdx.x;
    int lane = threadIdx.x & 63, wid = threadIdx.x >> 6;
    int v = (i < n) ? degi[i] : 0;
    int x = v;
#pragma unroll
    for (int s = 1; s < 64; s <<= 1) {
        int y = __shfl_up(x, s, 64);
        if (lane >= s) x += y;
    }
    __shared__ int ws[4];
    if (lane == 63) ws[wid] = x;
    __syncthreads();
    int pre = bpre[blockIdx.x];
    for (int w2 = 0; w2 < wid; ++w2) pre += ws[w2];
    if (i < n) { int e = pre + x - v; offs[i] = e; cur[i] = e; }
    if (i == 0) offs[n] = total;
}

// ---- permute all 3E edges into dst-sorted CSR order, unified node ids ----
__global__ void permute3_kernel(const int* __restrict__ up, const int* __restrict__ ut,
                                const int* __restrict__ ug,
                                const float* __restrict__ dinv, int* __restrict__ cur,
                                Edge* __restrict__ ep, int NP, int NT, int E) {
    int i = blockIdx.x * blockDim.x + threadIdx.x;
    if (i >= 3 * E) return;
    int g = i / E;
    int j = i - g * E;
    const int* edge = (g == 0) ? up : (g == 1) ? ut : ug;
    int base = (g == 0) ? 0 : (g == 1) ? NP : NP + NT;
    int s = edge[j] + base, t = edge[E + j] + base;
    int p = atomicAdd(&cur[t], 1);
    Edge e;
    e.s = s;
    e.w = dinv[s] * dinv[t];
    ep[p] = e;
}

// ---- conv layer 1 over ALL nodes: x1[n] = sum_in emb[src]*w (bf16 in/out) ----
__global__ void conv_csr1(const int* __restrict__ offs, const Edge* __restrict__ ep,
                          const ushort4* __restrict__ xin, ushort4* __restrict__ xout, int N) {
    int gid = blockIdx.x * blockDim.x + threadIdx.x;
    int n = gid >> 4, l = gid & 15;
    if (n >= N) return;
    int beg = offs[n], end = offs[n + 1];
    float4 acc = {0.f, 0.f, 0.f, 0.f};
    int k = beg;
    for (; k + 1 < end; k += 2) {
        Edge e0 = ep[k], e1 = ep[k + 1];
        ushort4 u0 = xin[(size_t)e0.s * 16 + l];
        ushort4 u1 = xin[(size_t)e1.s * 16 + l];
        acc = fma4(u2f4(u0), e0.w, acc);
        acc = fma4(u2f4(u1), e1.w, acc);
    }
    if (k < end) {
        Edge e0 = ep[k];
        acc = fma4(u2f4(xin[(size_t)e0.s * 16 + l]), e0.w, acc);
    }
    xout[(size_t)n * 16 + l] = f2u4(acc);
}

// ---- conv layer 2 + epilogue over ALL nodes: out[n]=(emb+x1+conv(x1))/3 ----
__global__ void conv_csr2(const int* __restrict__ offs, const Edge* __restrict__ ep,
                          const ushort4* __restrict__ emb, const ushort4* __restrict__ x1,
                          ushort4* __restrict__ out, int N) {
    int gid = blockIdx.x * blockDim.x + threadIdx.x;
    int n = gid >> 4, l = gid & 15;
    if (n >= N) return;
    int beg = offs[n], end = offs[n + 1];
    float4 acc = {0.f, 0.f, 0.f, 0.f};
    int k = beg;
    for (; k + 1 < end; k += 2) {
        Edge e0 = ep[k], e1 = ep[k + 1];
        ushort4 u0 = x1[(size_t)e0.s * 16 + l];
        ushort4 u1 = x1[(size_t)e1.s * 16 + l];
        acc = fma4(u2f4(u0), e0.w, acc);
        acc = fma4(u2f4(u1), e1.w, acc);
    }
    if (k < end) {
        Edge e0 = ep[k];
        acc = fma4(u2f4(x1[(size_t)e0.s * 16 + l]), e0.w, acc);
    }
    size_t idx = (size_t)n * 16 + l;
    float4 em = u2f4(emb[idx]), x = u2f4(x1[idx]);
    const float third = 1.0f / 3.0f;
    float4 o;
    o.x = (em.x + x.x + acc.x) * third;
    o.y = (em.y + x.y + acc.y) * third;
    o.z = (em.z + x.z + acc.z) * third;
    o.w = (em.w + x.w + acc.w) * third;
    out[idx] = f2u4(o);
}

// ---- final: 2 edges per 16-lane group; bf16 node rows (128 B each) ----
__global__ void final_kernel(const int* __restrict__ up_e, const int* __restrict__ ut_e,
                             const int* __restrict__ utag_e,
                             const float* __restrict__ src_feat, const float* __restrict__ dst_feat,
                             const ushort4* __restrict__ O,
                             const float4* __restrict__ W_s4, const float4* __restrict__ b_s4,
                             const float4* __restrict__ W_d4, const float4* __restrict__ b_d4,
                             float* __restrict__ out, int E, int NP, int NT) {
    int gid = blockIdx.x * blockDim.x + threadIdx.x;
    int grp = gid >> 4;
    int l = gid & 15;
    int e0 = grp * 2;
    if (e0 >= E) return;
    int e1 = e0 + 1;
    bool has1 = (e1 < E);
    int e1c = has1 ? e1 : e0;
    int lane = threadIdx.x & 63;
    int gbase = lane & 48;

    // unified node ids
    int sp0 = up_e[e0],        dp0 = up_e[E + e0];
    int st0 = ut_e[e0] + NP,   dt0 = ut_e[E + e0] + NP;
    int sg0 = utag_e[e0] + NP + NT, dg0 = utag_e[E + e0] + NP + NT;
    int sp1 = up_e[e1c],       dp1 = up_e[E + e1c];
    int st1 = ut_e[e1c] + NP,  dt1 = ut_e[E + e1c] + NP;
    int sg1 = utag_e[e1c] + NP + NT, dg1 = utag_e[E + e1c] + NP + NT;

    // one feature scalar per lane, broadcast via shfl in the FMA loop
    float f_s0 = src_feat[(size_t)e0 * 16 + l];
    float f_d0 = dst_feat[(size_t)e0 * 16 + l];
    float f_s1 = src_feat[(size_t)e1c * 16 + l];
    float f_d1 = dst_feat[(size_t)e1c * 16 + l];

    // issue all 12 row gathers up front (independent 8 B/lane streams)
    ushort4 ap0 = O[(size_t)sp0 * 16 + l];
    ushort4 at0 = O[(size_t)st0 * 16 + l];
    ushort4 ag0 = O[(size_t)sg0 * 16 + l];
    ushort4 bp0 = O[(size_t)dp0 * 16 + l];
    ushort4 bt0 = O[(size_t)dt0 * 16 + l];
    ushort4 bg0 = O[(size_t)dg0 * 16 + l];
    ushort4 ap1 = O[(size_t)sp1 * 16 + l];
    ushort4 at1 = O[(size_t)st1 * 16 + l];
    ushort4 ag1 = O[(size_t)sg1 * 16 + l];
    ushort4 bp1 = O[(size_t)dp1 * 16 + l];
    ushort4 bt1 = O[(size_t)dt1 * 16 + l];
    ushort4 bg1 = O[(size_t)dg1 * 16 + l];

    float4 fs0 = b_s4[l], fd0 = b_d4[l];
    float4 fs1 = fs0,     fd1 = fd0;
#pragma unroll
    for (int k = 0; k < 16; ++k) {
        float4 ws = W_s4[k * 16 + l];
        float4 wd = W_d4[k * 16 + l];
        float a0 = __shfl(f_s0, gbase + k, 64);
        float c0 = __shfl(f_d0, gbase + k, 64);
        float a1 = __shfl(f_s1, gbase + k, 64);
        float c1 = __shfl(f_d1, gbase + k, 64);
        fs0 = fma4(ws, a0, fs0); fd0 = fma4(wd, c0, fd0);
        fs1 = fma4(ws, a1, fs1); fd1 = fma4(wd, c1, fd1);
    }

    const float third = 1.0f / 3.0f;
    float4 P, Q;
    float4 vp = u2f4(ap0), vt = u2f4(at0), vg = u2f4(ag0);
    P.x = (vp.x + vt.x + vg.x) * third + fs0.x;
    P.y = (vp.y + vt.y + vg.y) * third + fs0.y;
    P.z = (vp.z + vt.z + vg.z) * third + fs0.z;
    P.w = (vp.w + vt.w + vg.w) * third + fs0.w;
    vp = u2f4(bp0); vt = u2f4(bt0); vg = u2f4(bg0);
    Q.x = (vp.x + vt.x + vg.x) * third + fd0.x;
    Q.y = (vp.y + vt.y + vg.y) * third + fd0.y;
    Q.z = (vp.z + vt.z + vg.z) * third + fd0.z;
    Q.w = (vp.w + vt.w + vg.w) * third + fd0.w;
    float prod0 = P.x * Q.x + P.y * Q.y + P.z * Q.z + P.w * Q.w;

    vp = u2f4(ap1); vt = u2f4(at1); vg = u2f4(ag1);
    P.x = (vp.x + vt.x + vg.x) * third + fs1.x;
    P.y = (vp.y + vt.y + vg.y) * third + fs1.y;
    P.z = (vp.z + vt.z + vg.z) * third + fs1.z;
    P.w = (vp.w + vt.w + vg.w) * third + fs1.w;
    vp = u2f4(bp1); vt = u2f4(bt1); vg = u2f4(bg1);
    Q.x = (vp.x + vt.x + vg.x) * third + fd1.x;
    Q.y = (vp.y + vt.y + vg.y) * third + fd1.y;
    Q.z = (vp.z + vt.z + vg.z) * third + fd1.z;
    Q.w = (vp.w + vt.w + vg.w) * third + fd1.w;
    float prod1 = P.x * Q.x + P.y * Q.y + P.z * Q.z + P.w * Q.w;

    prod0 += __shfl_xor(prod0, 8, 64);
    prod0 += __shfl_xor(prod0, 4, 64);
    prod0 += __shfl_xor(prod0, 2, 64);
    prod0 += __shfl_xor(prod0, 1, 64);
    prod1 += __shfl_xor(prod1, 8, 64);
    prod1 += __shfl_xor(prod1, 4, 64);
    prod1 += __shfl_xor(prod1, 2, 64);
    prod1 += __shfl_xor(prod1, 1, 64);
    if (l == 0) {
        out[e0] = prod0;
        if (has1) out[e1] = prod1;
    }
}

extern "C" void kernel_launch(void* const* d_in, const int* in_sizes, int n_in,
                              void* d_out, int out_size, void* d_ws, size_t ws_size,
                              hipStream_t stream) {
    const int*   up_e     = (const int*)d_in[0];
    const int*   ut_e     = (const int*)d_in[1];
    const int*   utag_e   = (const int*)d_in[2];
    const float* src_feat = (const float*)d_in[3];
    const float* dst_feat = (const float*)d_in[4];
    const float* up_emb   = (const float*)d_in[5];
    const float* ut_emb   = (const float*)d_in[6];
    const float* utag_emb = (const float*)d_in[7];
    const float* W_src    = (const float*)d_in[8];
    const float* b_src    = (const float*)d_in[9];
    const float* W_dst    = (const float*)d_in[10];
    const float* b_dst    = (const float*)d_in[11];
    float* out = (float*)d_out;

    const int E  = in_sizes[0] / 2;
    const int NP = in_sizes[5] / DIM;
    const int NT = in_sizes[6] / DIM;
    const int NG = in_sizes[7] / DIM;
    const int NTOT = NP + NT + NG;
    const int NB = (NTOT + 255) / 256;          // scan blocks

    // ---- workspace layout ----
    char* w = (char*)d_ws;
    int*  degi = (int*)w;                       w += (size_t)NTOT * 4;
    int*  offs = (int*)w;                       w += (size_t)(NTOT + 1) * 4;
    int*  cur  = (int*)w;                       w += (size_t)NTOT * 4;
    int*  bsum = (int*)w;                       w += (size_t)1024 * 4;
    float* dinv = (float*)w;                    w += (size_t)NTOT * 4;
    w = (char*)(((uintptr_t)w + 15) & ~(uintptr_t)15);
    Edge* ep   = (Edge*)w;                      w += (size_t)3 * E * sizeof(Edge);
    w = (char*)(((uintptr_t)w + 15) & ~(uintptr_t)15);
    ushort4* embh = (ushort4*)w;                w += (size_t)NTOT * 16 * 8;   // bf16 emb
    ushort4* x1h  = (ushort4*)w;                w += (size_t)NTOT * 16 * 8;   // bf16 x1
    ushort4* outh = (ushort4*)w;                // bf16 aggregated node table

    const int BT = 256;

    // degree counts (dst = edge[1] = second half of each edge array)
    hipMemsetAsync(degi, 0, (size_t)NTOT * 4, stream);
    deg3_kernel<<<dim3((3 * E + BT - 1) / BT), dim3(BT), 0, stream>>>(
        up_e + E, ut_e + E, utag_e + E, degi, NP, NT, E);
    dinv_kernel<<<dim3((NTOT + BT - 1) / BT), dim3(BT), 0, stream>>>(degi, dinv, NTOT);

    // convert emb tables to unified bf16
    cvt3_kernel<<<dim3((NTOT * 16 + BT - 1) / BT), dim3(BT), 0, stream>>>(
        (const float4*)up_emb, (const float4*)ut_emb, (const float4*)utag_emb,
        embh, NP, NT, NG);

    // global parallel exclusive scan over all nodes
    block_sums<<<dim3(NB), dim3(BT), 0, stream>>>(degi, bsum, NTOT);
    scan_bsums<<<dim3(1), dim3(1024), 0, stream>>>(bsum, NB);
    scatter_offs<<<dim3(NB), dim3(BT), 0, stream>>>(degi, bsum, offs, cur, NTOT, 3 * E);

    // single CSR build over all 3E edges (unified node ids)
    permute3_kernel<<<dim3((3 * E + BT - 1) / BT), dim3(BT), 0, stream>>>(
        up_e, ut_e, utag_e, dinv, cur, ep, NP, NT, E);

    // conv layers over ALL nodes in one launch each
    int nb = ((size_t)NTOT * 16 + BT - 1) / BT;
    conv_csr1<<<dim3(nb), dim3(BT), 0, stream>>>(offs, ep, embh, x1h, NTOT);
    conv_csr2<<<dim3(nb), dim3(BT), 0, stream>>>(offs, ep, embh, x1h, outh, NTOT);

    // final: 2 edges per 16-lane group
    int groups = (E + 1) / 2;
    final_kernel<<<dim3(((size_t)groups * 16 + BT - 1) / BT), dim3(BT), 0, stream>>>(
        up_e, ut_e, utag_e, src_feat, dst_feat, outh,
        (const float4*)W_src, (const float4*)b_src,
        (const float4*)W_dst, (const float4*)b_dst, out, E, NP, NT);
}

// Round 5
// 446.662 us; speedup vs baseline: 2.7690x; 1.1279x over previous
//
#include <hip/hip_runtime.h>

#define DIM 64

__device__ __forceinline__ float bf2f(unsigned short u) {
    union { unsigned int i; float f; } v; v.i = ((unsigned int)u) << 16; return v.f;
}
__device__ __forceinline__ unsigned short f2bf(float f) {
    union { float f; unsigned int i; } v; v.f = f;
    unsigned int r = v.i + 0x7fff + ((v.i >> 16) & 1);   // RNE (no NaN inputs here)
    return (unsigned short)(r >> 16);
}
__device__ __forceinline__ float4 u2f4(ushort4 u) {
    float4 f; f.x = bf2f(u.x); f.y = bf2f(u.y); f.z = bf2f(u.z); f.w = bf2f(u.w);
    return f;
}
__device__ __forceinline__ ushort4 f2u4(float4 f) {
    ushort4 u; u.x = f2bf(f.x); u.y = f2bf(f.y); u.z = f2bf(f.z); u.w = f2bf(f.w);
    return u;
}
__device__ __forceinline__ float4 fma4(float4 a, float s, float4 c) {
    c.x = fmaf(a.x, s, c.x); c.y = fmaf(a.y, s, c.y);
    c.z = fmaf(a.z, s, c.z); c.w = fmaf(a.w, s, c.w);
    return c;
}

// ---- fused: degree count (first 3E threads) + emb fp32->bf16 convert ----
__global__ void deg_cvt_kernel(const int* __restrict__ d0, const int* __restrict__ d1,
                               const int* __restrict__ d2, int* __restrict__ degi,
                               const float4* __restrict__ e0, const float4* __restrict__ e1,
                               const float4* __restrict__ e2, ushort4* __restrict__ embh,
                               int NP, int NT, int NG, int E) {
    int i = blockIdx.x * blockDim.x + threadIdx.x;
    int degN = 3 * E;
    if (i < degN) {
        int g = i / E;
        int j = i - g * E;
        const int* dd = (g == 0) ? d0 : (g == 1) ? d1 : d2;
        int base = (g == 0) ? 0 : (g == 1) ? NP : NP + NT;
        atomicAdd(&degi[base + dd[j]], 1);
        return;
    }
    int i2 = i - degN;
    int np16 = NP * 16, nt16 = NT * 16, ng16 = NG * 16;
    if (i2 >= np16 + nt16 + ng16) return;
    const float4* s; int j;
    if (i2 < np16)              { s = e0; j = i2; }
    else if (i2 < np16 + nt16)  { s = e1; j = i2 - np16; }
    else                        { s = e2; j = i2 - np16 - nt16; }
    embh[i2] = f2u4(s[j]);
}

// ---- parallel scan, stage 1: per-block (256-elem) sums ----
__global__ void block_sums(const int* __restrict__ degi, int* __restrict__ bsum, int n) {
    int i = blockIdx.x * 256 + threadIdx.x;
    int v = (i < n) ? degi[i] : 0;
#pragma unroll
    for (int s = 1; s < 64; s <<= 1) v += __shfl_xor(v, s, 64);
    __shared__ int ws[4];
    if ((threadIdx.x & 63) == 0) ws[threadIdx.x >> 6] = v;
    __syncthreads();
    if (threadIdx.x == 0) bsum[blockIdx.x] = ws[0] + ws[1] + ws[2] + ws[3];
}

// ---- stage 2: exclusive scan of block sums (single block, nb <= 1024) ----
__global__ void scan_bsums(int* __restrict__ bsum, int nb) {
    int lane = threadIdx.x & 63, wid = threadIdx.x >> 6;
    int v = (threadIdx.x < nb) ? bsum[threadIdx.x] : 0;
    int x = v;
#pragma unroll
    for (int s = 1; s < 64; s <<= 1) {
        int y = __shfl_up(x, s, 64);
        if (lane >= s) x += y;
    }
    __shared__ int ws[16];
    if (lane == 63) ws[wid] = x;
    __syncthreads();
    int pre = 0;
    for (int w2 = 0; w2 < wid; ++w2) pre += ws[w2];
    if (threadIdx.x < nb) bsum[threadIdx.x] = pre + x - v;   // exclusive
}

// ---- stage 3: global exclusive offsets + cursor copy + dinv ----
__global__ void scatter_offs(const int* __restrict__ degi, const int* __restrict__ bpre,
                             int* __restrict__ offs, int* __restrict__ cur,
                             float* __restrict__ dinv, int n, int total) {
    int i = blockIdx.x * 256 + threadIdx.x;
    int lane = threadIdx.x & 63, wid = threadIdx.x >> 6;
    int v = (i < n) ? degi[i] : 0;
    int x = v;
#pragma unroll
    for (int s = 1; s < 64; s <<= 1) {
        int y = __shfl_up(x, s, 64);
        if (lane >= s) x += y;
    }
    __shared__ int ws[4];
    if (lane == 63) ws[wid] = x;
    __syncthreads();
    int pre = bpre[blockIdx.x];
    for (int w2 = 0; w2 < wid; ++w2) pre += ws[w2];
    if (i < n) {
        int e = pre + x - v;
        offs[i] = e; cur[i] = e;
        dinv[i] = (v > 0) ? rsqrtf((float)v) : 0.0f;
    }
    if (i == 0) offs[n] = total;
}

// ---- permute all 3E edges into dst-sorted CSR order (4 B src-index payload) ----
__global__ void permute3_kernel(const int* __restrict__ up, const int* __restrict__ ut,
                                const int* __restrict__ ug, int* __restrict__ cur,
                                int* __restrict__ ei, int NP, int NT, int E) {
    int i = blockIdx.x * blockDim.x + threadIdx.x;
    if (i >= 3 * E) return;
    int g = i / E;
    int j = i - g * E;
    const int* edge = (g == 0) ? up : (g == 1) ? ut : ug;
    int base = (g == 0) ? 0 : (g == 1) ? NP : NP + NT;
    int s = edge[j] + base, t = edge[E + j] + base;
    int p = atomicAdd(&cur[t], 1);
    ei[p] = s;
}

// ---- conv layer 1: x1[n] = dinv[n] * sum_in emb[s]*dinv[s]  (bf16 rows) ----
__global__ void conv_csr1(const int* __restrict__ offs, const int* __restrict__ ei,
                          const float* __restrict__ dinv,
                          const ushort4* __restrict__ xin, ushort4* __restrict__ xout, int N) {
    int gid = blockIdx.x * blockDim.x + threadIdx.x;
    int n = gid >> 4, l = gid & 15;
    if (n >= N) return;
    int beg = offs[n], end = offs[n + 1];
    float4 acc = {0.f, 0.f, 0.f, 0.f};
    int k = beg;
    for (; k + 3 < end; k += 4) {
        int s0 = ei[k], s1 = ei[k + 1], s2 = ei[k + 2], s3 = ei[k + 3];
        float w0 = dinv[s0], w1 = dinv[s1], w2 = dinv[s2], w3 = dinv[s3];
        ushort4 u0 = xin[(size_t)s0 * 16 + l];
        ushort4 u1 = xin[(size_t)s1 * 16 + l];
        ushort4 u2 = xin[(size_t)s2 * 16 + l];
        ushort4 u3 = xin[(size_t)s3 * 16 + l];
        acc = fma4(u2f4(u0), w0, acc);
        acc = fma4(u2f4(u1), w1, acc);
        acc = fma4(u2f4(u2), w2, acc);
        acc = fma4(u2f4(u3), w3, acc);
    }
    for (; k < end; ++k) {
        int s = ei[k];
        acc = fma4(u2f4(xin[(size_t)s * 16 + l]), dinv[s], acc);
    }
    float sc = dinv[n];
    float4 r; r.x = acc.x * sc; r.y = acc.y * sc; r.z = acc.z * sc; r.w = acc.w * sc;
    xout[(size_t)n * 16 + l] = f2u4(r);
}

// ---- conv layer 2 + epilogue: out[n] = (emb + x1 + dinv[n]*sum x1[s]*dinv[s]) / 3 ----
__global__ void conv_csr2(const int* __restrict__ offs, const int* __restrict__ ei,
                          const float* __restrict__ dinv,
                          const ushort4* __restrict__ emb, const ushort4* __restrict__ x1,
                          ushort4* __restrict__ out, int N) {
    int gid = blockIdx.x * blockDim.x + threadIdx.x;
    int n = gid >> 4, l = gid & 15;
    if (n >= N) return;
    int beg = offs[n], end = offs[n + 1];
    float4 acc = {0.f, 0.f, 0.f, 0.f};
    int k = beg;
    for (; k + 3 < end; k += 4) {
        int s0 = ei[k], s1 = ei[k + 1], s2 = ei[k + 2], s3 = ei[k + 3];
        float w0 = dinv[s0], w1 = dinv[s1], w2 = dinv[s2], w3 = dinv[s3];
        ushort4 u0 = x1[(size_t)s0 * 16 + l];
        ushort4 u1 = x1[(size_t)s1 * 16 + l];
        ushort4 u2 = x1[(size_t)s2 * 16 + l];
        ushort4 u3 = x1[(size_t)s3 * 16 + l];
        acc = fma4(u2f4(u0), w0, acc);
        acc = fma4(u2f4(u1), w1, acc);
        acc = fma4(u2f4(u2), w2, acc);
        acc = fma4(u2f4(u3), w3, acc);
    }
    for (; k < end; ++k) {
        int s = ei[k];
        acc = fma4(u2f4(x1[(size_t)s * 16 + l]), dinv[s], acc);
    }
    float sc = dinv[n];
    size_t idx = (size_t)n * 16 + l;
    float4 em = u2f4(emb[idx]), x = u2f4(x1[idx]);
    const float third = 1.0f / 3.0f;
    float4 o;
    o.x = (em.x + x.x + acc.x * sc) * third;
    o.y = (em.y + x.y + acc.y * sc) * third;
    o.z = (em.z + x.z + acc.z * sc) * third;
    o.w = (em.w + x.w + acc.w * sc) * third;
    out[idx] = f2u4(o);
}

// ---- final: 4 edges per 16-lane group; bf16 node rows ----
__global__ void final_kernel(const int* __restrict__ up_e, const int* __restrict__ ut_e,
                             const int* __restrict__ utag_e,
                             const float* __restrict__ src_feat, const float* __restrict__ dst_feat,
                             const ushort4* __restrict__ O,
                             const float4* __restrict__ W_s4, const float4* __restrict__ b_s4,
                             const float4* __restrict__ W_d4, const float4* __restrict__ b_d4,
                             float* __restrict__ out, int E, int NP, int NT) {
    int gid = blockIdx.x * blockDim.x + threadIdx.x;
    int grp = gid >> 4;
    int l = gid & 15;
    int e0 = grp * 4;
    if (e0 >= E) return;
    int lane = threadIdx.x & 63;
    int gbase = lane & 48;

    ushort4 as[4][3], bs[4][3];
    float fsc[4], fdc[4];
#pragma unroll
    for (int j = 0; j < 4; ++j) {
        int e = e0 + j; if (e > E - 1) e = E - 1;
        int sp = up_e[e],             dp = up_e[E + e];
        int st = ut_e[e] + NP,        dt = ut_e[E + e] + NP;
        int sg = utag_e[e] + NP + NT, dg = utag_e[E + e] + NP + NT;
        as[j][0] = O[(size_t)sp * 16 + l];
        as[j][1] = O[(size_t)st * 16 + l];
        as[j][2] = O[(size_t)sg * 16 + l];
        bs[j][0] = O[(size_t)dp * 16 + l];
        bs[j][1] = O[(size_t)dt * 16 + l];
        bs[j][2] = O[(size_t)dg * 16 + l];
        fsc[j] = src_feat[(size_t)e * 16 + l];
        fdc[j] = dst_feat[(size_t)e * 16 + l];
    }

    float4 fs[4], fd[4];
    float4 bsv = b_s4[l], bdv = b_d4[l];
#pragma unroll
    for (int j = 0; j < 4; ++j) { fs[j] = bsv; fd[j] = bdv; }

#pragma unroll
    for (int k = 0; k < 16; ++k) {
        float4 ws = W_s4[k * 16 + l];
        float4 wd = W_d4[k * 16 + l];
#pragma unroll
        for (int j = 0; j < 4; ++j) {
            float a = __shfl(fsc[j], gbase + k, 64);
            float c = __shfl(fdc[j], gbase + k, 64);
            fs[j] = fma4(ws, a, fs[j]);
            fd[j] = fma4(wd, c, fd[j]);
        }
    }

    const float third = 1.0f / 3.0f;
    float prod[4];
#pragma unroll
    for (int j = 0; j < 4; ++j) {
        float4 vp = u2f4(as[j][0]), vt = u2f4(as[j][1]), vg = u2f4(as[j][2]);
        float4 P, Q;
        P.x = (vp.x + vt.x + vg.x) * third + fs[j].x;
        P.y = (vp.y + vt.y + vg.y) * third + fs[j].y;
        P.z = (vp.z + vt.z + vg.z) * third + fs[j].z;
        P.w = (vp.w + vt.w + vg.w) * third + fs[j].w;
        vp = u2f4(bs[j][0]); vt = u2f4(bs[j][1]); vg = u2f4(bs[j][2]);
        Q.x = (vp.x + vt.x + vg.x) * third + fd[j].x;
        Q.y = (vp.y + vt.y + vg.y) * third + fd[j].y;
        Q.z = (vp.z + vt.z + vg.z) * third + fd[j].z;
        Q.w = (vp.w + vt.w + vg.w) * third + fd[j].w;
        float p = P.x * Q.x + P.y * Q.y + P.z * Q.z + P.w * Q.w;
        p += __shfl_xor(p, 8, 64);
        p += __shfl_xor(p, 4, 64);
        p += __shfl_xor(p, 2, 64);
        p += __shfl_xor(p, 1, 64);
        prod[j] = p;
    }
    if (l == 0) {
#pragma unroll
        for (int j = 0; j < 4; ++j)
            if (e0 + j < E) out[e0 + j] = prod[j];
    }
}

extern "C" void kernel_launch(void* const* d_in, const int* in_sizes, int n_in,
                              void* d_out, int out_size, void* d_ws, size_t ws_size,
                              hipStream_t stream) {
    const int*   up_e     = (const int*)d_in[0];
    const int*   ut_e     = (const int*)d_in[1];
    const int*   utag_e   = (const int*)d_in[2];
    const float* src_feat = (const float*)d_in[3];
    const float* dst_feat = (const float*)d_in[4];
    const float* up_emb   = (const float*)d_in[5];
    const float* ut_emb   = (const float*)d_in[6];
    const float* utag_emb = (const float*)d_in[7];
    const float* W_src    = (const float*)d_in[8];
    const float* b_src    = (const float*)d_in[9];
    const float* W_dst    = (const float*)d_in[10];
    const float* b_dst    = (const float*)d_in[11];
    float* out = (float*)d_out;

    const int E  = in_sizes[0] / 2;
    const int NP = in_sizes[5] / DIM;
    const int NT = in_sizes[6] / DIM;
    const int NG = in_sizes[7] / DIM;
    const int NTOT = NP + NT + NG;
    const int NB = (NTOT + 255) / 256;          // scan blocks

    // ---- workspace layout ----
    char* w = (char*)d_ws;
    int*  degi = (int*)w;                       w += (size_t)NTOT * 4;
    int*  offs = (int*)w;                       w += (size_t)(NTOT + 1) * 4;
    int*  cur  = (int*)w;                       w += (size_t)NTOT * 4;
    int*  bsum = (int*)w;                       w += (size_t)1024 * 4;
    float* dinv = (float*)w;                    w += (size_t)NTOT * 4;
    w = (char*)(((uintptr_t)w + 127) & ~(uintptr_t)127);
    int*  ei   = (int*)w;                       w += (size_t)3 * E * 4;
    w = (char*)(((uintptr_t)w + 127) & ~(uintptr_t)127);
    ushort4* embh = (ushort4*)w;                w += (size_t)NTOT * 16 * 8;   // bf16 emb
    ushort4* x1h  = (ushort4*)w;                w += (size_t)NTOT * 16 * 8;   // bf16 x1
    ushort4* outh = (ushort4*)w;                // bf16 aggregated node table

    const int BT = 256;

    hipMemsetAsync(degi, 0, (size_t)NTOT * 4, stream);

    // fused degree count + emb bf16 convert
    {
        long long tot = 3LL * E + (long long)NTOT * 16;
        deg_cvt_kernel<<<dim3((tot + BT - 1) / BT), dim3(BT), 0, stream>>>(
            up_e + E, ut_e + E, utag_e + E, degi,
            (const float4*)up_emb, (const float4*)ut_emb, (const float4*)utag_emb,
            embh, NP, NT, NG, E);
    }

    // global parallel exclusive scan over all nodes (+ dinv)
    block_sums<<<dim3(NB), dim3(BT), 0, stream>>>(degi, bsum, NTOT);
    scan_bsums<<<dim3(1), dim3(1024), 0, stream>>>(bsum, NB);
    scatter_offs<<<dim3(NB), dim3(BT), 0, stream>>>(degi, bsum, offs, cur, dinv, NTOT, 3 * E);

    // single CSR build over all 3E edges (4 B payload)
    permute3_kernel<<<dim3((3 * E + BT - 1) / BT), dim3(BT), 0, stream>>>(
        up_e, ut_e, utag_e, cur, ei, NP, NT, E);

    // conv layers over ALL nodes
    int nb = ((size_t)NTOT * 16 + BT - 1) / BT;
    conv_csr1<<<dim3(nb), dim3(BT), 0, stream>>>(offs, ei, dinv, embh, x1h, NTOT);
    conv_csr2<<<dim3(nb), dim3(BT), 0, stream>>>(offs, ei, dinv, embh, x1h, outh, NTOT);

    // final: 4 edges per 16-lane group
    long long groups = (E + 3) / 4;
    final_kernel<<<dim3((groups * 16 + BT - 1) / BT), dim3(BT), 0, stream>>>(
        up_e, ut_e, utag_e, src_feat, dst_feat, outh,
        (const float4*)W_src, (const float4*)b_src,
        (const float4*)W_dst, (const float4*)b_dst, out, E, NP, NT);
}